// Round 3
// baseline (296.370 us; speedup 1.0000x reference)
//
#include <hip/hip_runtime.h>
#include <hip/hip_bf16.h>
#include <stdint.h>

#define B_SZ 4
#define T_LEN 8192
#define D_DIM 512
#define M_TOT 32768
#define CHUNK 128
#define NCH 64    // chunks per batch
#define SCS 132   // f32 scan-tile LDS stride: 4*132 % 32 == 16 -> 2-way max (free)

typedef __attribute__((ext_vector_type(8))) short bf16x8v;
typedef __attribute__((ext_vector_type(4))) float f32x4v;

__device__ __forceinline__ unsigned short f2bf(float f) {
  unsigned int u = __float_as_uint(f);
  u += 0x7fffu + ((u >> 16) & 1u);
  return (unsigned short)(u >> 16);
}
__device__ __forceinline__ float bf2f(unsigned short b) {
  return __uint_as_float(((unsigned int)b) << 16);
}
__device__ __forceinline__ float sigmoidf_(float x) { return 1.0f / (1.0f + expf(-x)); }

// async global->LDS, 16B per lane; lds base must be wave-uniform (m97 pattern)
__device__ __forceinline__ void g2l16(const void* g, void* l) {
  __builtin_amdgcn_global_load_lds((const __attribute__((address_space(1))) void*)g,
                                   (__attribute__((address_space(3))) void*)l, 16, 0, 0);
}

// ---------------------------------------------------------------------------
// prep: blocks 0..1023 -> Wb,Wc to bf16 | block 1024 -> powA[i][ch]=a^(i+1) f32
//       blocks 1025.. -> x (f32) to bf16 (into d_out scratch region)
__global__ void prep_k(const float* __restrict__ x, const float* __restrict__ Wb,
                       const float* __restrict__ Wc, const float* __restrict__ A,
                       unsigned short* __restrict__ wbf, float* __restrict__ powA,
                       unsigned short* __restrict__ xbf) {
  const int b = blockIdx.x;
  const int tid = threadIdx.x;
  if (b < 1024) {
    int i = b * 256 + tid;
    wbf[i] = f2bf(Wb[i]);
    wbf[262144 + i] = f2bf(Wc[i]);
  } else if (b == 1024) {
#pragma unroll
    for (int s = 0; s < 2; ++s) {
      int ch = s * 256 + tid;
      float a = sigmoidf_(A[ch]);
      float p = a;
      for (int i = 0; i < CHUNK; ++i) {
        powA[i * D_DIM + ch] = p;
        p *= a;
      }
    }
  } else {
    size_t idx = ((size_t)(b - 1025) * 256 + tid) * 8;
    float4 v0 = *(const float4*)&x[idx];
    float4 v1 = *(const float4*)&x[idx + 4];
    uint4 o;
    o.x = (unsigned)f2bf(v0.x) | ((unsigned)f2bf(v0.y) << 16);
    o.y = (unsigned)f2bf(v0.z) | ((unsigned)f2bf(v0.w) << 16);
    o.z = (unsigned)f2bf(v1.x) | ((unsigned)f2bf(v1.y) << 16);
    o.w = (unsigned)f2bf(v1.z) | ((unsigned)f2bf(v1.w) << 16);
    *(uint4*)&xbf[idx] = o;
  }
}

// ---------------------------------------------------------------------------
// In-place chunk-carry prefix (validated r2): cst holds local finals on entry,
// state entering each chunk on exit. grid=B_SZ, block=512.
__global__ void carry_k(const float* __restrict__ A, float* __restrict__ cst) {
  const int ch = threadIdx.x;
  const int bi = blockIdx.x;
  float a = sigmoidf_(A[ch]);
  float p = a;
#pragma unroll
  for (int i = 0; i < 7; ++i) p *= p;  // a^128
  float H = 0.f;
#pragma unroll 8
  for (int c = 0; c < NCH; ++c) {
    size_t off = ((size_t)bi * NCH + c) * D_DIM + ch;
    float lf = cst[off];
    cst[off] = H;
    H = fmaf(p, H, lf);
  }
}

// ---------------------------------------------------------------------------
// fix: h[g*128+t][ch] += powA[t][ch] * carry[g][ch], in place (bf16).
// grid = 256 chunks, block = 512.
__global__ void fix_k(unsigned short* __restrict__ h, const float* __restrict__ cst,
                      const float* __restrict__ powA) {
  const int g = blockIdx.x;
  const int u = threadIdx.x & 63;   // channel octet
  const int rs = threadIdx.x >> 6;  // 0..7
  float car[8];
  *(float4*)car = *(const float4*)&cst[(size_t)g * D_DIM + u * 8];
  *(float4*)(car + 4) = *(const float4*)&cst[(size_t)g * D_DIM + u * 8 + 4];
#pragma unroll
  for (int p = 0; p < 16; ++p) {
    int row = p * 8 + rs;
    size_t off = ((size_t)g * CHUNK + row) * D_DIM + u * 8;
    uint4 hv = *(const uint4*)&h[off];
    float4 p0 = *(const float4*)&powA[row * D_DIM + u * 8];
    float4 p1 = *(const float4*)&powA[row * D_DIM + u * 8 + 4];
    const unsigned* hw = (const unsigned*)&hv;
    const float* pf = (const float*)&p0;  // p0,p1 contiguous? not guaranteed; handle separately
    unsigned ow[4];
#pragma unroll
    for (int q = 0; q < 4; ++q) {
      float pa = (q < 2) ? ((q == 0) ? p0.x : p0.z) : ((q == 2) ? p1.x : p1.z);
      float pb = (q < 2) ? ((q == 0) ? p0.y : p0.w) : ((q == 2) ? p1.y : p1.w);
      float o0 = fmaf(pa, car[2 * q], bf2f((unsigned short)(hw[q] & 0xffff)));
      float o1 = fmaf(pb, car[2 * q + 1], bf2f((unsigned short)(hw[q] >> 16)));
      ow[q] = (unsigned)f2bf(o0) | ((unsigned)f2bf(o1) << 16);
    }
    (void)pf;
    *(uint4*)&h[off] = make_uint4(ow[0], ow[1], ow[2], ow[3]);
  }
}

// ---------------------------------------------------------------------------
// m97-style 128x128xBK64 bf16 GEMM vs transposed weights, global_load_lds
// staging, linear LDS, 2 barriers/K-step.
// MODE 0: epilogue = fused chunk scan (two 64-row halves), writes h_local bf16
//         + chunk finals to cst. C unused.
// MODE 1: epilogue = per-wave LDS-transposed coalesced f32 C store.
template <int MODE>
__global__ __launch_bounds__(256, 4) void gemm_k(
    const unsigned short* __restrict__ Abf, const unsigned short* __restrict__ Bw,
    float* __restrict__ C, const float* __restrict__ Ad,
    unsigned short* __restrict__ hOut, float* __restrict__ cst) {
  __shared__ union {
    unsigned short st[2][128 * 64];  // A,B staging (32 KB), linear [row][64]
    float sc[64 * SCS];              // MODE0 scan half-tile (33.8 KB)
    float tp[4][16 * 68];            // MODE1 per-wave transpose (17.4 KB)
  } sm;

  const int tid = threadIdx.x;
  const int lane = tid & 63;
  const int w = tid >> 6;
  const int wm = (w >> 1) * 64;
  const int wn = (w & 1) * 64;
  const int bm = blockIdx.y * 128;
  const int bn = blockIdx.x * 128;
  const int l15 = lane & 15;
  const int g4 = lane >> 4;
  const int srow = lane >> 3;        // gload_lds: lane -> row offset
  const int scol = (lane & 7) * 8;   // gload_lds: lane -> k element

  f32x4v acc[4][4] = {};

  for (int k0 = 0; k0 < 512; k0 += 64) {
#pragma unroll
    for (int q = 0; q < 4; ++q) {
      int r = w * 32 + q * 8;  // wave-uniform row base
      g2l16(&Abf[(size_t)(bm + r + srow) * 512 + k0 + scol], &sm.st[0][r * 64]);
      g2l16(&Bw[(size_t)(bn + r + srow) * 512 + k0 + scol], &sm.st[1][r * 64]);
    }
    __syncthreads();
#pragma unroll
    for (int ks = 0; ks < 2; ++ks) {
      bf16x8v af[4], bf_[4];
#pragma unroll
      for (int i = 0; i < 4; ++i)
        af[i] = *(const bf16x8v*)&sm.st[0][(wm + i * 16 + l15) * 64 + ks * 32 + g4 * 8];
#pragma unroll
      for (int j = 0; j < 4; ++j)
        bf_[j] = *(const bf16x8v*)&sm.st[1][(wn + j * 16 + l15) * 64 + ks * 32 + g4 * 8];
#pragma unroll
      for (int i = 0; i < 4; ++i)
#pragma unroll
        for (int j = 0; j < 4; ++j)
          acc[i][j] = __builtin_amdgcn_mfma_f32_16x16x32_bf16(af[i], bf_[j], acc[i][j], 0, 0, 0);
    }
    __syncthreads();
  }

  if constexpr (MODE == 0) {
    // fused chunk-local scan, two 64-row halves to keep LDS small
    float a = 0.f, hcar = 0.f;
    if (tid < 128) a = sigmoidf_(Ad[bn + tid]);
#pragma unroll
    for (int half = 0; half < 2; ++half) {
      if ((w >> 1) == half) {  // waves owning these 64 rows scatter acc
#pragma unroll
        for (int i = 0; i < 4; ++i)
#pragma unroll
          for (int j = 0; j < 4; ++j)
#pragma unroll
            for (int r = 0; r < 4; ++r)
              sm.sc[(i * 16 + g4 * 4 + r) * SCS + wn + j * 16 + l15] = acc[i][j][r];
      }
      __syncthreads();
      if (tid < 128) {
        float h = hcar;
#pragma unroll 8
        for (int t = 0; t < 64; ++t) {
          h = fmaf(a, h, sm.sc[t * SCS + tid]);
          sm.sc[t * SCS + tid] = h;
        }
        hcar = h;
      }
      __syncthreads();
      // write this half's 64 rows of h_local as bf16 (coalesced uint4)
#pragma unroll
      for (int p = 0; p < 4; ++p) {
        int uu = p * 256 + tid;
        int row = uu >> 4, c8 = (uu & 15) * 8;
        const float* s = &sm.sc[row * SCS + c8];
        unsigned w0 = (unsigned)f2bf(s[0]) | ((unsigned)f2bf(s[1]) << 16);
        unsigned w1 = (unsigned)f2bf(s[2]) | ((unsigned)f2bf(s[3]) << 16);
        unsigned w2 = (unsigned)f2bf(s[4]) | ((unsigned)f2bf(s[5]) << 16);
        unsigned w3 = (unsigned)f2bf(s[6]) | ((unsigned)f2bf(s[7]) << 16);
        *(uint4*)&hOut[(size_t)(bm + half * 64 + row) * D_DIM + bn + c8] =
            make_uint4(w0, w1, w2, w3);
      }
      __syncthreads();  // protect sc before next half's scatter
    }
    if (tid < 128) cst[(size_t)blockIdx.y * D_DIM + bn + tid] = hcar;  // local final
  } else {
    // coalesced C store via per-wave LDS transpose (validated r2)
    float* tp = sm.tp[w];
#pragma unroll
    for (int i = 0; i < 4; ++i) {
#pragma unroll
      for (int j = 0; j < 4; ++j)
#pragma unroll
        for (int r = 0; r < 4; ++r)
          tp[(g4 * 4 + r) * 68 + j * 16 + l15] = acc[i][j][r];
#pragma unroll
      for (int p = 0; p < 4; ++p) {
        f32x4v v = *(const f32x4v*)&tp[(p * 4 + g4) * 68 + l15 * 4];
        *(f32x4v*)&C[(size_t)(bm + wm + i * 16 + p * 4 + g4) * 512 + bn + wn + l15 * 4] = v;
      }
    }
  }
}

// ---------------------------------------------------------------------------
extern "C" void kernel_launch(void* const* d_in, const int* in_sizes, int n_in,
                              void* d_out, int out_size, void* d_ws, size_t ws_size,
                              hipStream_t stream) {
  const float* x = (const float*)d_in[0];
  const float* W_B = (const float*)d_in[1];
  const float* W_C = (const float*)d_in[2];
  const float* A = (const float*)d_in[3];
  float* out = (float*)d_out;
  char* ws = (char*)d_ws;

  // ws: [0,512K) Wb | [512K,1M) Wc | [1M,1.25M) powA f32 | [1.25M,1.75M) cst |
  //     [2M,34M) h bf16.   x_bf16 lives in d_out's first 32MB (dead before GEMM2).
  unsigned short* Wb = (unsigned short*)ws;
  unsigned short* Wc = Wb + 262144;
  float* powA = (float*)(ws + 0x100000);
  float* cst = (float*)(ws + 0x140000);
  unsigned short* hbf = (unsigned short*)(ws + 0x200000);
  unsigned short* xbf = (unsigned short*)d_out;

  prep_k<<<1025 + 8192, 256, 0, stream>>>(x, W_B, W_C, A, Wb, powA, xbf);

  dim3 gg(D_DIM / 128, M_TOT / 128);  // (4, 256)
  gemm_k<0><<<gg, 256, 0, stream>>>(xbf, Wb, nullptr, A, hbf, cst);
  carry_k<<<B_SZ, 512, 0, stream>>>(A, cst);
  fix_k<<<256, 512, 0, stream>>>(hbf, cst, powA);
  gemm_k<1><<<gg, 256, 0, stream>>>(hbf, Wc, out, A, nullptr, cst);
}

// Round 4
// 142.220 us; speedup vs baseline: 2.0839x; 2.0839x over previous
//
#include <hip/hip_runtime.h>
#include <hip/hip_bf16.h>
#include <stdint.h>

#define B_SZ 4
#define T_LEN 8192
#define D_DIM 512
#define M_TOT 32768
#define CHUNK 128
#define NCH 64    // chunks per batch
#define SCS 132   // f32 scan-tile LDS stride: 2-way max (free)

typedef __attribute__((ext_vector_type(8))) short bf16x8v;
typedef __attribute__((ext_vector_type(4))) float f32x4v;

__device__ __forceinline__ unsigned short f2bf(float f) {
  unsigned int u = __float_as_uint(f);
  u += 0x7fffu + ((u >> 16) & 1u);
  return (unsigned short)(u >> 16);
}
__device__ __forceinline__ float bf2f(unsigned short b) {
  return __uint_as_float(((unsigned int)b) << 16);
}
__device__ __forceinline__ float sigmoidf_(float x) { return 1.0f / (1.0f + expf(-x)); }

// async global->LDS, 16B/lane; LDS dest wave-uniform base + lane*16 (linear)
__device__ __forceinline__ void g2l16(const void* g, void* l) {
  __builtin_amdgcn_global_load_lds((const __attribute__((address_space(1))) void*)g,
                                   (__attribute__((address_space(3))) void*)l, 16, 0, 0);
}

// ---------------------------------------------------------------------------
// prep: blocks 0..1023 -> Wb,Wc to bf16 | block 1024 -> powA[i][ch]=a^(i+1)
//       blocks 1025.. -> x (f32) to bf16 (into d_out scratch region)
__global__ void prep_k(const float* __restrict__ x, const float* __restrict__ Wb,
                       const float* __restrict__ Wc, const float* __restrict__ A,
                       unsigned short* __restrict__ wbf, float* __restrict__ powA,
                       unsigned short* __restrict__ xbf) {
  const int b = blockIdx.x;
  const int tid = threadIdx.x;
  if (b < 1024) {
    int i = b * 256 + tid;
    wbf[i] = f2bf(Wb[i]);
    wbf[262144 + i] = f2bf(Wc[i]);
  } else if (b == 1024) {
#pragma unroll
    for (int s = 0; s < 2; ++s) {
      int ch = s * 256 + tid;
      float a = sigmoidf_(A[ch]);
      float p = a;
      for (int i = 0; i < CHUNK; ++i) {
        powA[i * D_DIM + ch] = p;
        p *= a;
      }
    }
  } else {
    size_t idx = ((size_t)(b - 1025) * 256 + tid) * 8;
    float4 v0 = *(const float4*)&x[idx];
    float4 v1 = *(const float4*)&x[idx + 4];
    uint4 o;
    o.x = (unsigned)f2bf(v0.x) | ((unsigned)f2bf(v0.y) << 16);
    o.y = (unsigned)f2bf(v0.z) | ((unsigned)f2bf(v0.w) << 16);
    o.z = (unsigned)f2bf(v1.x) | ((unsigned)f2bf(v1.y) << 16);
    o.w = (unsigned)f2bf(v1.z) | ((unsigned)f2bf(v1.w) << 16);
    *(uint4*)&xbf[idx] = o;
  }
}

// ---------------------------------------------------------------------------
// In-place chunk-carry prefix: cst holds local finals on entry, state entering
// each chunk on exit. grid=B_SZ, block=512.
__global__ void carry_k(const float* __restrict__ A, float* __restrict__ cst) {
  const int ch = threadIdx.x;
  const int bi = blockIdx.x;
  float a = sigmoidf_(A[ch]);
  float p = a;
#pragma unroll
  for (int i = 0; i < 7; ++i) p *= p;  // a^128
  float H = 0.f;
#pragma unroll 8
  for (int c = 0; c < NCH; ++c) {
    size_t off = ((size_t)bi * NCH + c) * D_DIM + ch;
    float lf = cst[off];
    cst[off] = H;
    H = fmaf(p, H, lf);
  }
}

// ---------------------------------------------------------------------------
// fix: h[g*128+t][ch] += powA[t][ch] * carry[g][ch], in place (bf16).
__global__ void fix_k(unsigned short* __restrict__ h, const float* __restrict__ cst,
                      const float* __restrict__ powA) {
  const int g = blockIdx.x;
  const int u = threadIdx.x & 63;
  const int rs = threadIdx.x >> 6;
  float car[8];
  *(float4*)car = *(const float4*)&cst[(size_t)g * D_DIM + u * 8];
  *(float4*)(car + 4) = *(const float4*)&cst[(size_t)g * D_DIM + u * 8 + 4];
#pragma unroll
  for (int p = 0; p < 16; ++p) {
    int row = p * 8 + rs;
    size_t off = ((size_t)g * CHUNK + row) * D_DIM + u * 8;
    uint4 hv = *(const uint4*)&h[off];
    float4 p0 = *(const float4*)&powA[row * D_DIM + u * 8];
    float4 p1 = *(const float4*)&powA[row * D_DIM + u * 8 + 4];
    const unsigned* hw = (const unsigned*)&hv;
    unsigned ow[4];
#pragma unroll
    for (int q = 0; q < 4; ++q) {
      float pa = (q < 2) ? ((q == 0) ? p0.x : p0.z) : ((q == 2) ? p1.x : p1.z);
      float pb = (q < 2) ? ((q == 0) ? p0.y : p0.w) : ((q == 2) ? p1.y : p1.w);
      float o0 = fmaf(pa, car[2 * q], bf2f((unsigned short)(hw[q] & 0xffff)));
      float o1 = fmaf(pb, car[2 * q + 1], bf2f((unsigned short)(hw[q] >> 16)));
      ow[q] = (unsigned)f2bf(o0) | ((unsigned)f2bf(o1) << 16);
    }
    *(uint4*)&h[off] = make_uint4(ow[0], ow[1], ow[2], ow[3]);
  }
}

// ---------------------------------------------------------------------------
// 128x128xBK64 bf16 GEMM vs transposed weights. global_load_lds staging with
// FRAGMENT-ORDERED LDS: each 16-row x 32-k subtile is 1KB where lane l's 16B
// hold its MFMA fragment (row=l&15, k-oct=l>>4). Global source is pre-permuted
// per-lane (m173 pattern); LDS dest stays linear. All fragment ds_read_b128s
// are base + lane*16 -> conflict-free.
// MODE 0: epilogue = fused chunk scan -> h_local bf16 + chunk finals.
// MODE 1: epilogue = per-wave LDS-transposed coalesced f32 C store.
template <int MODE>
__global__ __launch_bounds__(256, 4) void gemm_k(
    const unsigned short* __restrict__ Abf, const unsigned short* __restrict__ Bw,
    float* __restrict__ C, const float* __restrict__ Ad,
    unsigned short* __restrict__ hOut, float* __restrict__ cst) {
  __shared__ union {
    unsigned short st[2][8192];  // A,B staging, 16 subtiles x 512 shorts each
    float sc[64 * SCS];          // MODE0 scan half-tile (33.8 KB)
    float tp[4][16 * 68];        // MODE1 per-wave transpose
  } sm;

  const int tid = threadIdx.x;
  const int lane = tid & 63;
  const int w = tid >> 6;
  const int wm = (w >> 1) * 64;
  const int wn = (w & 1) * 64;
  const int bm = blockIdx.y * 128;
  const int bn = blockIdx.x * 128;
  const int l15 = lane & 15;
  const int g4 = lane >> 4;
  const int smA = (w >> 1) * 4;  // this wave's A subtile row-group base (wm/16)
  const int smB = (w & 1) * 4;   // B subtile base (wn/16)

  // Per-lane fragment-order global sources. Wave w stages subtile rows
  // w*2+q (q=0,1), k-halves sk=0,1, for both A and B.
  const unsigned short* aS[2][2];
  const unsigned short* bS[2][2];
#pragma unroll
  for (int q = 0; q < 2; ++q)
#pragma unroll
    for (int sk = 0; sk < 2; ++sk) {
      aS[q][sk] = Abf + (size_t)(bm + (w * 2 + q) * 16 + l15) * 512 + sk * 32 + g4 * 8;
      bS[q][sk] = Bw + (size_t)(bn + (w * 2 + q) * 16 + l15) * 512 + sk * 32 + g4 * 8;
    }

  f32x4v acc[4][4] = {};

#pragma unroll
  for (int k0 = 0; k0 < 512; k0 += 64) {
#pragma unroll
    for (int q = 0; q < 2; ++q)
#pragma unroll
      for (int sk = 0; sk < 2; ++sk) {
        int sub = (w * 2 + q) * 2 + sk;  // wave-uniform subtile id
        g2l16(aS[q][sk], &sm.st[0][sub * 512]);
        g2l16(bS[q][sk], &sm.st[1][sub * 512]);
        aS[q][sk] += 64;
        bS[q][sk] += 64;
      }
    __syncthreads();
#pragma unroll
    for (int ks = 0; ks < 2; ++ks) {
      bf16x8v af[4], bf_[4];
#pragma unroll
      for (int i = 0; i < 4; ++i)
        af[i] = *(const bf16x8v*)&sm.st[0][((smA + i) * 2 + ks) * 512 + lane * 8];
#pragma unroll
      for (int j = 0; j < 4; ++j)
        bf_[j] = *(const bf16x8v*)&sm.st[1][((smB + j) * 2 + ks) * 512 + lane * 8];
#pragma unroll
      for (int i = 0; i < 4; ++i)
#pragma unroll
        for (int j = 0; j < 4; ++j)
          acc[i][j] = __builtin_amdgcn_mfma_f32_16x16x32_bf16(af[i], bf_[j], acc[i][j], 0, 0, 0);
    }
    __syncthreads();
  }

  if constexpr (MODE == 0) {
    // fused chunk-local scan, two 64-row halves
    float a = 0.f, hcar = 0.f;
    if (tid < 128) a = sigmoidf_(Ad[bn + tid]);
#pragma unroll
    for (int half = 0; half < 2; ++half) {
      if ((w >> 1) == half) {
#pragma unroll
        for (int i = 0; i < 4; ++i)
#pragma unroll
          for (int j = 0; j < 4; ++j)
#pragma unroll
            for (int r = 0; r < 4; ++r)
              sm.sc[(i * 16 + g4 * 4 + r) * SCS + wn + j * 16 + l15] = acc[i][j][r];
      }
      __syncthreads();
      if (tid < 128) {
        float h = hcar;
#pragma unroll 8
        for (int t = 0; t < 64; ++t) {
          h = fmaf(a, h, sm.sc[t * SCS + tid]);
          sm.sc[t * SCS + tid] = h;
        }
        hcar = h;
      }
      __syncthreads();
#pragma unroll
      for (int p = 0; p < 4; ++p) {
        int uu = p * 256 + tid;
        int row = uu >> 4, c8 = (uu & 15) * 8;
        const float* s = &sm.sc[row * SCS + c8];
        unsigned w0 = (unsigned)f2bf(s[0]) | ((unsigned)f2bf(s[1]) << 16);
        unsigned w1 = (unsigned)f2bf(s[2]) | ((unsigned)f2bf(s[3]) << 16);
        unsigned w2 = (unsigned)f2bf(s[4]) | ((unsigned)f2bf(s[5]) << 16);
        unsigned w3 = (unsigned)f2bf(s[6]) | ((unsigned)f2bf(s[7]) << 16);
        *(uint4*)&hOut[(size_t)(bm + half * 64 + row) * D_DIM + bn + c8] =
            make_uint4(w0, w1, w2, w3);
      }
      __syncthreads();
    }
    if (tid < 128) cst[(size_t)blockIdx.y * D_DIM + bn + tid] = hcar;
  } else {
    // coalesced C store via per-wave LDS transpose
    float* tp = sm.tp[w];
#pragma unroll
    for (int i = 0; i < 4; ++i) {
#pragma unroll
      for (int j = 0; j < 4; ++j)
#pragma unroll
        for (int r = 0; r < 4; ++r)
          tp[(g4 * 4 + r) * 68 + j * 16 + l15] = acc[i][j][r];
#pragma unroll
      for (int p = 0; p < 4; ++p) {
        f32x4v v = *(const f32x4v*)&tp[(p * 4 + g4) * 68 + l15 * 4];
        *(f32x4v*)&C[(size_t)(bm + wm + i * 16 + p * 4 + g4) * 512 + bn + wn + l15 * 4] = v;
      }
    }
  }
}

// ---------------------------------------------------------------------------
extern "C" void kernel_launch(void* const* d_in, const int* in_sizes, int n_in,
                              void* d_out, int out_size, void* d_ws, size_t ws_size,
                              hipStream_t stream) {
  const float* x = (const float*)d_in[0];
  const float* W_B = (const float*)d_in[1];
  const float* W_C = (const float*)d_in[2];
  const float* A = (const float*)d_in[3];
  float* out = (float*)d_out;
  char* ws = (char*)d_ws;

  unsigned short* Wb = (unsigned short*)ws;
  unsigned short* Wc = Wb + 262144;
  float* powA = (float*)(ws + 0x100000);
  float* cst = (float*)(ws + 0x140000);
  unsigned short* hbf = (unsigned short*)(ws + 0x200000);
  unsigned short* xbf = (unsigned short*)d_out;  // dead before GEMM2's C-write

  prep_k<<<1025 + 8192, 256, 0, stream>>>(x, W_B, W_C, A, Wb, powA, xbf);

  dim3 gg(D_DIM / 128, M_TOT / 128);  // (4, 256)
  gemm_k<0><<<gg, 256, 0, stream>>>(xbf, Wb, nullptr, A, hbf, cst);
  carry_k<<<B_SZ, 512, 0, stream>>>(A, cst);
  fix_k<<<256, 512, 0, stream>>>(hbf, cst, powA);
  gemm_k<1><<<gg, 256, 0, stream>>>(hbf, Wc, out, A, nullptr, cst);
}

// Round 5
// 132.157 us; speedup vs baseline: 2.2426x; 1.0761x over previous
//
#include <hip/hip_runtime.h>
#include <hip/hip_bf16.h>
#include <stdint.h>

#define B_SZ 4
#define T_LEN 8192
#define D_DIM 512
#define M_TOT 32768
#define CHUNK 128
#define NCH 64    // chunks per batch
#define SCS 132   // f32 scan-tile LDS stride: 2-way max (free)

typedef __attribute__((ext_vector_type(8))) short bf16x8v;
typedef __attribute__((ext_vector_type(4))) float f32x4v;

__device__ __forceinline__ unsigned short f2bf(float f) {
  unsigned int u = __float_as_uint(f);
  u += 0x7fffu + ((u >> 16) & 1u);
  return (unsigned short)(u >> 16);
}
__device__ __forceinline__ float bf2f(unsigned short b) {
  return __uint_as_float(((unsigned int)b) << 16);
}
__device__ __forceinline__ float sigmoidf_(float x) { return 1.0f / (1.0f + expf(-x)); }

// async global->LDS, 16B/lane; LDS dest wave-uniform base + lane*16 (linear)
__device__ __forceinline__ void g2l16(const void* g, void* l) {
  __builtin_amdgcn_global_load_lds((const __attribute__((address_space(1))) void*)g,
                                   (__attribute__((address_space(3))) void*)l, 16, 0, 0);
}

// ---------------------------------------------------------------------------
// prep: blocks 0..1023 -> Wb,Wc to bf16 | block 1024 -> powA[i][ch]=a^(i+1)
//       blocks 1025.. -> x (f32) to bf16 (into d_out scratch region)
__global__ void prep_k(const float* __restrict__ x, const float* __restrict__ Wb,
                       const float* __restrict__ Wc, const float* __restrict__ A,
                       unsigned short* __restrict__ wbf, float* __restrict__ powA,
                       unsigned short* __restrict__ xbf) {
  const int b = blockIdx.x;
  const int tid = threadIdx.x;
  if (b < 1024) {
    int i = b * 256 + tid;
    wbf[i] = f2bf(Wb[i]);
    wbf[262144 + i] = f2bf(Wc[i]);
  } else if (b == 1024) {
#pragma unroll
    for (int s = 0; s < 2; ++s) {
      int ch = s * 256 + tid;
      float a = sigmoidf_(A[ch]);
      float p = a;
      for (int i = 0; i < CHUNK; ++i) {
        powA[i * D_DIM + ch] = p;
        p *= a;
      }
    }
  } else {
    size_t idx = ((size_t)(b - 1025) * 256 + tid) * 8;
    float4 v0 = *(const float4*)&x[idx];
    float4 v1 = *(const float4*)&x[idx + 4];
    uint4 o;
    o.x = (unsigned)f2bf(v0.x) | ((unsigned)f2bf(v0.y) << 16);
    o.y = (unsigned)f2bf(v0.z) | ((unsigned)f2bf(v0.w) << 16);
    o.z = (unsigned)f2bf(v1.x) | ((unsigned)f2bf(v1.y) << 16);
    o.w = (unsigned)f2bf(v1.z) | ((unsigned)f2bf(v1.w) << 16);
    *(uint4*)&xbf[idx] = o;
  }
}

// ---------------------------------------------------------------------------
// In-place chunk-carry prefix. grid=B_SZ, block=512.
__global__ void carry_k(const float* __restrict__ A, float* __restrict__ cst) {
  const int ch = threadIdx.x;
  const int bi = blockIdx.x;
  float a = sigmoidf_(A[ch]);
  float p = a;
#pragma unroll
  for (int i = 0; i < 7; ++i) p *= p;  // a^128
  float H = 0.f;
#pragma unroll 8
  for (int c = 0; c < NCH; ++c) {
    size_t off = ((size_t)bi * NCH + c) * D_DIM + ch;
    float lf = cst[off];
    cst[off] = H;
    H = fmaf(p, H, lf);
  }
}

// ---------------------------------------------------------------------------
// fix: h[g*128+t][ch] += powA[t][ch] * carry[g][ch], in place (bf16).
__global__ void fix_k(unsigned short* __restrict__ h, const float* __restrict__ cst,
                      const float* __restrict__ powA) {
  const int g = blockIdx.x;
  const int u = threadIdx.x & 63;
  const int rs = threadIdx.x >> 6;
  float car[8];
  *(float4*)car = *(const float4*)&cst[(size_t)g * D_DIM + u * 8];
  *(float4*)(car + 4) = *(const float4*)&cst[(size_t)g * D_DIM + u * 8 + 4];
#pragma unroll
  for (int p = 0; p < 16; ++p) {
    int row = p * 8 + rs;
    size_t off = ((size_t)g * CHUNK + row) * D_DIM + u * 8;
    uint4 hv = *(const uint4*)&h[off];
    float4 p0 = *(const float4*)&powA[row * D_DIM + u * 8];
    float4 p1 = *(const float4*)&powA[row * D_DIM + u * 8 + 4];
    const unsigned* hw = (const unsigned*)&hv;
    unsigned ow[4];
#pragma unroll
    for (int q = 0; q < 4; ++q) {
      float pa = (q < 2) ? ((q == 0) ? p0.x : p0.z) : ((q == 2) ? p1.x : p1.z);
      float pb = (q < 2) ? ((q == 0) ? p0.y : p0.w) : ((q == 2) ? p1.y : p1.w);
      float o0 = fmaf(pa, car[2 * q], bf2f((unsigned short)(hw[q] & 0xffff)));
      float o1 = fmaf(pb, car[2 * q + 1], bf2f((unsigned short)(hw[q] >> 16)));
      ow[q] = (unsigned)f2bf(o0) | ((unsigned)f2bf(o1) << 16);
    }
    *(uint4*)&h[off] = make_uint4(ow[0], ow[1], ow[2], ow[3]);
  }
}

// ---------------------------------------------------------------------------
// 128x128xBK64 bf16 GEMM, fragment-ordered gload_lds staging (r4-validated,
// conflict-free ds_reads), now DOUBLE-BUFFERED minimum-2-phase (T3-lite):
// issue next K-step's loads BEFORE computing current step; single
// __syncthreads per step drains an already-overlapped latency.
// XCD-bijective swizzle: the 4 N-tiles of an M-tile land on one XCD.
// MODE 0: epilogue = fused chunk scan -> h_local bf16 + chunk finals.
// MODE 1: epilogue = per-wave LDS-transposed coalesced f32 C store.
template <int MODE>
__global__ __launch_bounds__(256, 2) void gemm_k(
    const unsigned short* __restrict__ Abf, const unsigned short* __restrict__ Bw,
    float* __restrict__ C, const float* __restrict__ Ad,
    unsigned short* __restrict__ hOut, float* __restrict__ cst) {
  __shared__ union {
    unsigned short st[2][2][8192];  // [buf][A,B] 16 subtiles x 512 shorts (64 KB)
    float sc[64 * SCS];             // MODE0 scan half-tile (33.8 KB)
    float tp[4][16 * 68];           // MODE1 per-wave transpose
  } sm;

  const int tid = threadIdx.x;
  const int lane = tid & 63;
  const int w = tid >> 6;
  const int wm = (w >> 1) * 64;
  const int wn = (w & 1) * 64;

  // bijective XCD swizzle (grid 1024 = 8*128): consecutive work on one XCD,
  // n-major so the 4 N-tiles sharing an A-tile share that XCD's L2.
  const int flat = blockIdx.y * 4 + blockIdx.x;
  const int work = ((flat & 7) << 7) | (flat >> 3);
  const int mt = work >> 2;        // M-tile == scan chunk id
  const int bm = mt * 128;
  const int bn = (work & 3) * 128;

  const int l15 = lane & 15;
  const int g4 = lane >> 4;
  const int smA = (w >> 1) * 4;  // wave's A subtile group
  const int smB = (w & 1) * 4;   // wave's B subtile group

  // Fragment-order per-lane global sources (k0=0); lane l -> row l15, k-oct g4.
  const unsigned short* aB[2][2];
  const unsigned short* bB[2][2];
#pragma unroll
  for (int q = 0; q < 2; ++q)
#pragma unroll
    for (int sk = 0; sk < 2; ++sk) {
      aB[q][sk] = Abf + (size_t)(bm + (w * 2 + q) * 16 + l15) * 512 + sk * 32 + g4 * 8;
      bB[q][sk] = Bw + (size_t)(bn + (w * 2 + q) * 16 + l15) * 512 + sk * 32 + g4 * 8;
    }

  auto stage = [&](int buf, int k0) {
#pragma unroll
    for (int q = 0; q < 2; ++q) {
      int s0 = (w * 2 + q) * 2;  // wave-uniform subtile ids
      g2l16(aB[q][0] + k0, &sm.st[buf][0][s0 * 512]);
      g2l16(aB[q][1] + k0, &sm.st[buf][0][(s0 + 1) * 512]);
      g2l16(bB[q][0] + k0, &sm.st[buf][1][s0 * 512]);
      g2l16(bB[q][1] + k0, &sm.st[buf][1][(s0 + 1) * 512]);
    }
  };

  f32x4v acc[4][4] = {};

  stage(0, 0);
  __syncthreads();  // vmcnt(0) drain + barrier (prologue only full stall)
  int cur = 0;
#pragma unroll
  for (int t = 0; t < 8; ++t) {
    if (t < 7) stage(cur ^ 1, (t + 1) * 64);  // async loads fly under compute
#pragma unroll
    for (int ks = 0; ks < 2; ++ks) {
      bf16x8v af[4], bf_[4];
#pragma unroll
      for (int i = 0; i < 4; ++i)
        af[i] = *(const bf16x8v*)&sm.st[cur][0][((smA + i) * 2 + ks) * 512 + lane * 8];
#pragma unroll
      for (int j = 0; j < 4; ++j)
        bf_[j] = *(const bf16x8v*)&sm.st[cur][1][((smB + j) * 2 + ks) * 512 + lane * 8];
#pragma unroll
      for (int i = 0; i < 4; ++i)
#pragma unroll
        for (int j = 0; j < 4; ++j)
          acc[i][j] = __builtin_amdgcn_mfma_f32_16x16x32_bf16(af[i], bf_[j], acc[i][j], 0, 0, 0);
    }
    __syncthreads();  // drains overlapped stage loads; protects buffer reuse
    cur ^= 1;
  }

  if constexpr (MODE == 0) {
    // fused chunk-local scan, two 64-row halves
    float a = 0.f, hcar = 0.f;
    if (tid < 128) a = sigmoidf_(Ad[bn + tid]);
#pragma unroll
    for (int half = 0; half < 2; ++half) {
      if ((w >> 1) == half) {
#pragma unroll
        for (int i = 0; i < 4; ++i)
#pragma unroll
          for (int j = 0; j < 4; ++j)
#pragma unroll
            for (int r = 0; r < 4; ++r)
              sm.sc[(i * 16 + g4 * 4 + r) * SCS + wn + j * 16 + l15] = acc[i][j][r];
      }
      __syncthreads();
      if (tid < 128) {
        float h = hcar;
#pragma unroll 8
        for (int t = 0; t < 64; ++t) {
          h = fmaf(a, h, sm.sc[t * SCS + tid]);
          sm.sc[t * SCS + tid] = h;
        }
        hcar = h;
      }
      __syncthreads();
#pragma unroll
      for (int p = 0; p < 4; ++p) {
        int uu = p * 256 + tid;
        int row = uu >> 4, c8 = (uu & 15) * 8;
        const float* s = &sm.sc[row * SCS + c8];
        unsigned w0 = (unsigned)f2bf(s[0]) | ((unsigned)f2bf(s[1]) << 16);
        unsigned w1 = (unsigned)f2bf(s[2]) | ((unsigned)f2bf(s[3]) << 16);
        unsigned w2 = (unsigned)f2bf(s[4]) | ((unsigned)f2bf(s[5]) << 16);
        unsigned w3 = (unsigned)f2bf(s[6]) | ((unsigned)f2bf(s[7]) << 16);
        *(uint4*)&hOut[(size_t)(bm + half * 64 + row) * D_DIM + bn + c8] =
            make_uint4(w0, w1, w2, w3);
      }
      __syncthreads();
    }
    if (tid < 128) cst[(size_t)mt * D_DIM + bn + tid] = hcar;
  } else {
    // coalesced C store via per-wave LDS transpose
    float* tp = sm.tp[w];
#pragma unroll
    for (int i = 0; i < 4; ++i) {
#pragma unroll
      for (int j = 0; j < 4; ++j)
#pragma unroll
        for (int r = 0; r < 4; ++r)
          tp[(g4 * 4 + r) * 68 + j * 16 + l15] = acc[i][j][r];
#pragma unroll
      for (int p = 0; p < 4; ++p) {
        f32x4v v = *(const f32x4v*)&tp[(p * 4 + g4) * 68 + l15 * 4];
        *(f32x4v*)&C[(size_t)(bm + wm + i * 16 + p * 4 + g4) * 512 + bn + wn + l15 * 4] = v;
      }
    }
  }
}

// ---------------------------------------------------------------------------
extern "C" void kernel_launch(void* const* d_in, const int* in_sizes, int n_in,
                              void* d_out, int out_size, void* d_ws, size_t ws_size,
                              hipStream_t stream) {
  const float* x = (const float*)d_in[0];
  const float* W_B = (const float*)d_in[1];
  const float* W_C = (const float*)d_in[2];
  const float* A = (const float*)d_in[3];
  float* out = (float*)d_out;
  char* ws = (char*)d_ws;

  unsigned short* Wb = (unsigned short*)ws;
  unsigned short* Wc = Wb + 262144;
  float* powA = (float*)(ws + 0x100000);
  float* cst = (float*)(ws + 0x140000);
  unsigned short* hbf = (unsigned short*)(ws + 0x200000);
  unsigned short* xbf = (unsigned short*)d_out;  // dead before GEMM2's C-write

  prep_k<<<1025 + 8192, 256, 0, stream>>>(x, W_B, W_C, A, Wb, powA, xbf);

  dim3 gg(D_DIM / 128, M_TOT / 128);  // (4, 256)
  gemm_k<0><<<gg, 256, 0, stream>>>(xbf, Wb, nullptr, A, hbf, cst);
  carry_k<<<B_SZ, 512, 0, stream>>>(A, cst);
  fix_k<<<256, 512, 0, stream>>>(hbf, cst, powA);
  gemm_k<1><<<gg, 256, 0, stream>>>(hbf, Wc, out, A, nullptr, cst);
}